// Round 12
// baseline (6412.636 us; speedup 1.0000x reference)
//
#include <hip/hip_runtime.h>

typedef unsigned int u32;
typedef u32 u32x16 __attribute__((ext_vector_type(16)));

#define TT 2048
#define HD 256
#define G4 1024
#define NT 16
#define START_TAG 14
#define STOP_TAG 15
#define NEGV (-10000.0f)

__device__ __forceinline__ int sdot4e(u32 a, u32 b, int c) {
#if __has_builtin(__builtin_amdgcn_sdot4)
    return __builtin_amdgcn_sdot4((int)a, (int)b, c, false);
#else
    c += (int)(signed char)(a & 255) * (int)(signed char)(b & 255);
    c += (int)(signed char)((a >> 8) & 255) * (int)(signed char)((b >> 8) & 255);
    c += (int)(signed char)((a >> 16) & 255) * (int)(signed char)((b >> 16) & 255);
    c += (int)(signed char)(a >> 24) * (int)(signed char)(b >> 24);
    return c;
#endif
}
__device__ __forceinline__ float sigmf_(float x) { return 1.0f / (1.0f + __expf(-x)); }
__device__ __forceinline__ float tanhf_(float x) {
    float e = __expf(-2.0f * fabsf(x));
    return copysignf((1.0f - e) / (1.0f + e), x);
}

// K0: quantize w_hh to int8, per-row scale. One wave per row; lane packs u32
// (elems 4*lane..4*lane+3) -> wreg8[dir][row][64]. ALL weights now register-file
// (the 2-CU split halves per-thread weight footprint to 64 u32 -> fits in regs).
__global__ __launch_bounds__(256) void pack_q8(const float* whh_f, const float* whh_b,
                                               u32* wreg8, float* rowscale) {
    int lane = threadIdx.x & 63;
    int row = blockIdx.x * 4 + (threadIdx.x >> 6);   // 0..2047
    int dir = row >> 10, r = row & 1023;
    const float* w = (dir ? whh_b : whh_f) + (size_t)r * HD + lane * 4;
    float4 v = *((const float4*)w);
    float m = fmaxf(fmaxf(fabsf(v.x), fabsf(v.y)), fmaxf(fabsf(v.z), fabsf(v.w)));
    for (int off = 1; off < 64; off <<= 1) m = fmaxf(m, __shfl_xor(m, off, 64));
    float invs = m > 0.f ? 127.f / m : 0.f;
    int q0 = (int)rintf(v.x * invs), q1 = (int)rintf(v.y * invs);
    int q2 = (int)rintf(v.z * invs), q3 = (int)rintf(v.w * invs);
    u32 pk = (u32)(q0 & 255) | ((u32)(q1 & 255) << 8) |
             ((u32)(q2 & 255) << 16) | ((u32)(q3 & 255) << 24);
    wreg8[((size_t)(dir * 1024 + r)) * 64 + lane] = pk;
    if (lane == 0) rowscale[dir * 1024 + r] = m * (1.0f / (127.f * 64.f));
}

// K1: G[dir][t][r] = dot(embed[sent[t or T-1-t]], w_ih[r]) + b[r]   (f32 exact)
__global__ __launch_bounds__(256) void input_gemm(const int* sent, const float* embed,
                                                  const float* wih_f, const float* b_f,
                                                  const float* wih_b, const float* b_b,
                                                  float* G) {
    __shared__ float X[16][HD];   // 16KB
    __shared__ int rows[16];
    int tid = threadIdx.x;
    int dir = blockIdx.z;
    int t0 = blockIdx.x * 16;
    if (tid < 16) {
        int tg = t0 + tid;
        rows[tid] = sent[dir ? (TT - 1 - tg) : tg];
    }
    __syncthreads();
    for (int i = 0; i < 16; i++) X[i][tid] = embed[(size_t)rows[i] * HD + tid];
    __syncthreads();
    int r = blockIdx.y * 256 + tid;
    const float* wrow = (dir ? wih_b : wih_f) + (size_t)r * HD;
    float acc[16];
#pragma unroll
    for (int i = 0; i < 16; i++) acc[i] = 0.0f;
    for (int kc = 0; kc < HD / 4; kc++) {
        float4 w4 = ((const float4*)wrow)[kc];
#pragma unroll
        for (int i = 0; i < 16; i++) {
            float4 x4 = *((const float4*)&X[i][kc * 4]);
            acc[i] += w4.x * x4.x + w4.y * x4.y + w4.z * x4.z + w4.w * x4.w;
        }
    }
    float bias = (dir ? b_b : b_f)[r];
    for (int i = 0; i < 16; i++)
        G[((size_t)dir * TT + t0 + i) * G4 + r] = acc[i] + bias;
}

// 16-u32 dot block: W[0..15] vs h u32 at HB4[O..O+3] (uniform LDS broadcast)
#define DOT16B(A, W, HB4, O)                                       \
    {                                                              \
        uint4 pa = HB4[(O)];                                       \
        A = sdot4e(W[0], pa.x, A);  A = sdot4e(W[1], pa.y, A);     \
        A = sdot4e(W[2], pa.z, A);  A = sdot4e(W[3], pa.w, A);     \
        uint4 pb = HB4[(O) + 1];                                   \
        A = sdot4e(W[4], pb.x, A);  A = sdot4e(W[5], pb.y, A);     \
        A = sdot4e(W[6], pb.z, A);  A = sdot4e(W[7], pb.w, A);     \
        uint4 pc = HB4[(O) + 2];                                   \
        A = sdot4e(W[8], pc.x, A);  A = sdot4e(W[9], pc.y, A);     \
        A = sdot4e(W[10], pc.z, A); A = sdot4e(W[11], pc.w, A);    \
        uint4 pd = HB4[(O) + 3];                                   \
        A = sdot4e(W[12], pd.x, A); A = sdot4e(W[13], pd.y, A);    \
        A = sdot4e(W[14], pd.z, A); A = sdot4e(W[15], pd.w, A);    \
    }

// K2: LSTM recurrence split 2 CUs PER DIRECTION (grid=4: dir=blk>>1, half=blk&1).
// Block owns elements half*128..half*128+127 = 512 gate rows; 512 threads,
// 1 row each (gate=tid>>7, elem=half*128+(tid&127)). ALL 64 weight u32 live in
// FOUR NAMED u32x16 SSA regs (~85 VGPR demand <= proven 128 grant) -> zero LDS
// weight traffic (R8 spent ~500cyc/step on it), dot issue halves to 512 cyc/CU.
// Per-step cross-CU h-half exchange via global hx (parity dbuf) + device-scope
// release/acquire flags. Flags are memset to 0 on-stream each launch.
__global__ __launch_bounds__(512, 1)
void lstm_rec(const u32* wreg8, const float* rowscale, const float* G,
              const float* h0, const float* c0, float* H, u32* hx, int* flags) {
    __shared__ float act[512];               // activated gates
    __shared__ __align__(16) u32 h2q[2][64]; // parity-dbuf 256 int8 of h
    int tid = threadIdx.x;
    int dir = blockIdx.x >> 1, half = blockIdx.x & 1;
    int rown = ((tid >> 7) << 8) + (half << 7) + (tid & 127);
    int gate = tid >> 7;
    const u32x16* p = (const u32x16*)(wreg8 + ((size_t)dir * 1024 + rown) * 64);
    u32x16 w0 = p[0], w1 = p[1], w2 = p[2], w3 = p[3];
    float cr = rowscale[dir * 1024 + rown];
    float cst = 0.0f;
    if (tid < 128) cst = c0[dir * HD + (half << 7) + tid];
    if (tid < 256) {                          // both halves init h2q[1] locally
        float hv = h0[dir * HD + tid];
        hv = fminf(fmaxf(hv, -1.984375f), 1.984375f);
        int hq = ((int)rintf(hv * 64.f)) & 255;
        int b1 = __shfl_down(hq, 1, 64);
        int b2 = __shfl_down(hq, 2, 64);
        int b3 = __shfl_down(hq, 3, 64);
        if ((tid & 3) == 0)
            h2q[1][tid >> 2] = (u32)hq | ((u32)b1 << 8) | ((u32)b2 << 16) | ((u32)b3 << 24);
    }
    __syncthreads();
    const float* Gd = G + (size_t)dir * TT * G4;
    float* Hd = H + (size_t)dir * TT * HD;
    int myf = dir * 2 + half, pf = dir * 2 + (1 - half);
    u32* hx_my = hx + (size_t)myf * 64;          // [parity][32]
    const u32* hx_pt = hx + (size_t)pf * 64;
    for (int t = 0; t < TT; t++) {
        const uint4* hb4 = (const uint4*)&h2q[(t + 1) & 1][0];
        float g0 = Gd[(size_t)t * G4 + rown];
        int accA = 0, accB = 0;
        DOT16B(accA, w0, hb4, 0)  DOT16B(accB, w1, hb4, 4)
        DOT16B(accA, w2, hb4, 8)  DOT16B(accB, w3, hb4, 12)
        float e = (float)(accA + accB) * cr + g0;
        float a = (gate == 2) ? tanhf_(e) : sigmf_(e);   // wave-uniform (2 waves/gate)
        act[tid] = a;
        __syncthreads();                                 // B1
        if (tid < 128) {                                 // gate0 lanes: a = sig(i)
            float sf = act[128 + tid], tg = act[256 + tid], so = act[384 + tid];
            cst = sf * cst + a * tg;
            float h = so * tanhf_(cst);
            int hq = ((int)rintf(h * 64.f)) & 255;
            int b1 = __shfl_down(hq, 1, 64);
            int b2 = __shfl_down(hq, 2, 64);
            int b3 = __shfl_down(hq, 3, 64);
            if ((tid & 3) == 0) {
                u32 pk = (u32)hq | ((u32)b1 << 8) | ((u32)b2 << 16) | ((u32)b3 << 24);
                int idx = tid >> 2;                      // 0..31
                h2q[t & 1][(half << 5) + idx] = pk;      // own half -> LDS
                hx_my[((t & 1) << 5) + idx] = pk;        // own half -> global
                __threadfence();                         // make hx store visible
            }
            Hd[(size_t)t * HD + (half << 7) + tid] = h;  // after fence: not waited
        }
        __syncthreads();                                 // B2: all publishes fenced
        if (tid == 0)
            __hip_atomic_store(&flags[myf], t + 1, __ATOMIC_RELEASE,
                               __HIP_MEMORY_SCOPE_AGENT);
        if (tid < 32) {
            while (__hip_atomic_load(&flags[pf], __ATOMIC_ACQUIRE,
                                     __HIP_MEMORY_SCOPE_AGENT) < t + 1) {}
            u32 pv = __hip_atomic_load(&hx_pt[((t & 1) << 5) + tid], __ATOMIC_RELAXED,
                                       __HIP_MEMORY_SCOPE_AGENT);
            h2q[t & 1][((1 - half) << 5) + tid] = pv;    // partner half -> LDS
        }
        __syncthreads();                                 // B3: h2q[t&1] complete
    }
}

// K3: feats[t][n] = hf[t]·w_out[n][0:256] + hb_scan[T-1-t]·w_out[n][256:512] + b_out[n]
__global__ __launch_bounds__(256) void feats_kernel(const float* H, const float* w_out,
                                                    const float* b_out, float* feats) {
    int idx = blockIdx.x * blockDim.x + threadIdx.x;
    int t = idx >> 4, n = idx & 15;
    const float* hf = H + (size_t)t * HD;
    const float* hb = H + ((size_t)TT + (TT - 1 - t)) * HD;
    const float* w = w_out + (size_t)n * (2 * HD);
    float a = b_out[n];
    for (int k = 0; k < HD; k += 4) {
        float4 h4 = *((const float4*)&hf[k]);
        float4 w4 = *((const float4*)&w[k]);
        a += h4.x * w4.x + h4.y * w4.y + h4.z * w4.z + h4.w * w4.w;
    }
    for (int k = 0; k < HD; k += 4) {
        float4 h4 = *((const float4*)&hb[k]);
        float4 w4 = *((const float4*)&w[HD + k]);
        a += h4.x * w4.x + h4.y * w4.y + h4.z * w4.z + h4.w * w4.w;
    }
    feats[(size_t)t * NT + n] = a;
}

// K4: Viterbi + backtrack, single wave. Group result vft resident in all 4
// lanes of group n; one 4-gather shfl level + DPP butterfly per step.
__global__ __launch_bounds__(64) void viterbi_kernel(const float* feats, const float* trans,
                                                     float* out) {
    __shared__ float fl[4096];              // 16KB: 256 steps x 16 tags
    __shared__ float fvs[NT];
    __shared__ unsigned char bps[TT][NT];   // 32KB
    int lane = threadIdx.x;
    int n = lane >> 2, pg = lane & 3;
    float4 tr4 = *((const float4*)&trans[n * NT + pg * 4]);
    float vft = (n == START_TAG) ? 0.0f : NEGV;   // tag n's fv, replicated in group n
    for (int c = 0; c < TT / 256; c++) {
        float4 st[16];
        const float4* src = (const float4*)(feats + c * 4096);
#pragma unroll
        for (int i = 0; i < 16; i++) st[i] = src[i * 64 + lane];
#pragma unroll
        for (int i = 0; i < 16; i++) *((float4*)&fl[(i * 64 + lane) * 4]) = st[i];
        __syncthreads();
        for (int tt = 0; tt < 256; tt++) {
            int t = c * 256 + tt;
            float f0 = __shfl(vft, ((pg << 2) + 0) << 2, 64);
            float f1 = __shfl(vft, ((pg << 2) + 1) << 2, 64);
            float f2 = __shfl(vft, ((pg << 2) + 2) << 2, 64);
            float f3 = __shfl(vft, ((pg << 2) + 3) << 2, 64);
            float ft = fl[tt * 16 + n];
            float v = f0 + tr4.x; int bi = pg * 4 + 0;
            float v1 = f1 + tr4.y; if (v1 > v) { v = v1; bi = pg * 4 + 1; }
            float v2 = f2 + tr4.z; if (v2 > v) { v = v2; bi = pg * 4 + 2; }
            float v3 = f3 + tr4.w; if (v3 > v) { v = v3; bi = pg * 4 + 3; }
#pragma unroll
            for (int m = 1; m <= 2; m <<= 1) {   // DPP-speed; first-index tie-break
                float ov = __shfl_xor(v, m, 64);
                int ob = __shfl_xor(bi, m, 64);
                if (ov > v || (ov == v && ob < bi)) { v = ov; bi = ob; }
            }
            if (pg == 0) bps[t][n] = (unsigned char)bi;
            vft = v + ft;
        }
        __syncthreads();
    }
    if ((lane & 3) == 0) fvs[n] = vft;
    __syncthreads();
    if (lane == 0) {
        float best = -3.0e38f; int bt = 0;
        for (int p = 0; p < NT; p++) {
            float tv = fvs[p] + trans[STOP_TAG * NT + p];
            if (tv > best) { best = tv; bt = p; }
        }
        out[0] = best;
        int tag = bt;
        out[TT] = (float)tag;                  // path[T-1]
        for (int t = TT - 2; t >= 0; t--) {
            tag = bps[t + 1][tag];
            out[1 + t] = (float)tag;
        }
    }
}

extern "C" void kernel_launch(void* const* d_in, const int* in_sizes, int n_in,
                              void* d_out, int out_size, void* d_ws, size_t ws_size,
                              hipStream_t stream) {
    const int* sent = (const int*)d_in[0];
    const float* embed = (const float*)d_in[1];
    const float* wih_f = (const float*)d_in[2];
    const float* whh_f = (const float*)d_in[3];
    const float* b_f = (const float*)d_in[4];
    const float* wih_b = (const float*)d_in[5];
    const float* whh_b = (const float*)d_in[6];
    const float* b_b = (const float*)d_in[7];
    const float* w_out = (const float*)d_in[8];
    const float* b_out = (const float*)d_in[9];
    const float* trans = (const float*)d_in[10];
    const float* h0 = (const float*)d_in[11];
    const float* c0 = (const float*)d_in[12];
    float* out = (float*)d_out;
    char* ws = (char*)d_ws;

    float* G = (float*)(ws);                                    // 16MB
    float* H = (float*)(ws + (size_t)16 * 1024 * 1024);         // 4MB
    float* feats = (float*)(ws + (size_t)20 * 1024 * 1024);     // 128KB
    u32* wreg8 = (u32*)(ws + (size_t)21 * 1024 * 1024);         // 512KB
    float* rowscale = (float*)(ws + (size_t)21 * 1024 * 1024 + 768 * 1024);  // 8KB
    u32* hx = (u32*)(ws + (size_t)22 * 1024 * 1024);            // 1KB
    int* flags = (int*)(ws + (size_t)22 * 1024 * 1024 + 4096);  // 16B

    hipMemsetAsync(flags, 0, 16, stream);   // reset handshake flags each launch
    pack_q8<<<dim3(512), 256, 0, stream>>>(whh_f, whh_b, wreg8, rowscale);
    input_gemm<<<dim3(TT / 16, G4 / 256, 2), 256, 0, stream>>>(sent, embed, wih_f, b_f,
                                                               wih_b, b_b, G);
    lstm_rec<<<dim3(4), 512, 0, stream>>>(wreg8, rowscale, G, h0, c0, H, hx, flags);
    feats_kernel<<<dim3(TT * NT / 256), 256, 0, stream>>>(H, w_out, b_out, feats);
    viterbi_kernel<<<dim3(1), 64, 0, stream>>>(feats, trans, out);
}

// Round 13
// 2610.488 us; speedup vs baseline: 2.4565x; 2.4565x over previous
//
#include <hip/hip_runtime.h>

typedef unsigned int u32;
typedef u32 u32x8 __attribute__((ext_vector_type(8)));

#define TT 2048
#define HD 256
#define G4 1024
#define NT 16
#define START_TAG 14
#define STOP_TAG 15
#define NEGV (-10000.0f)

__device__ __forceinline__ int sdot4e(u32 a, u32 b, int c) {
#if __has_builtin(__builtin_amdgcn_sdot4)
    return __builtin_amdgcn_sdot4((int)a, (int)b, c, false);
#else
    c += (int)(signed char)(a & 255) * (int)(signed char)(b & 255);
    c += (int)(signed char)((a >> 8) & 255) * (int)(signed char)((b >> 8) & 255);
    c += (int)(signed char)((a >> 16) & 255) * (int)(signed char)((b >> 16) & 255);
    c += (int)(signed char)(a >> 24) * (int)(signed char)(b >> 24);
    return c;
#endif
}
__device__ __forceinline__ float sigmf_(float x) { return 1.0f / (1.0f + __expf(-x)); }
__device__ __forceinline__ float tanhf_(float x) {
    float e = __expf(-2.0f * fabsf(x));
    return copysignf((1.0f - e) / (1.0f + e), x);
}

// K0: quantize w_hh to int8, per-row scale. One wave per row; lane packs u32
// (elems 4*lane..4*lane+3) -> wreg8[dir][row][64]. ALL weights register-resident
// in the consumer (VGPR + AGPR overflow); no LDS weight file anymore.
__global__ __launch_bounds__(256) void pack_q8(const float* whh_f, const float* whh_b,
                                               u32* wreg8, float* rowscale) {
    int lane = threadIdx.x & 63;
    int row = blockIdx.x * 4 + (threadIdx.x >> 6);   // 0..2047
    int dir = row >> 10, r = row & 1023;
    const float* w = (dir ? whh_b : whh_f) + (size_t)r * HD + lane * 4;
    float4 v = *((const float4*)w);
    float m = fmaxf(fmaxf(fabsf(v.x), fabsf(v.y)), fmaxf(fabsf(v.z), fabsf(v.w)));
    for (int off = 1; off < 64; off <<= 1) m = fmaxf(m, __shfl_xor(m, off, 64));
    float invs = m > 0.f ? 127.f / m : 0.f;
    int q0 = (int)rintf(v.x * invs), q1 = (int)rintf(v.y * invs);
    int q2 = (int)rintf(v.z * invs), q3 = (int)rintf(v.w * invs);
    u32 pk = (u32)(q0 & 255) | ((u32)(q1 & 255) << 8) |
             ((u32)(q2 & 255) << 16) | ((u32)(q3 & 255) << 24);
    wreg8[((size_t)(dir * 1024 + r)) * 64 + lane] = pk;
    if (lane == 0) rowscale[dir * 1024 + r] = m * (1.0f / (127.f * 64.f));
}

// K1: G[dir][t][r] = dot(embed[sent[t or T-1-t]], w_ih[r]) + b[r]   (f32 exact)
__global__ __launch_bounds__(256) void input_gemm(const int* sent, const float* embed,
                                                  const float* wih_f, const float* b_f,
                                                  const float* wih_b, const float* b_b,
                                                  float* G) {
    __shared__ float X[16][HD];   // 16KB
    __shared__ int rows[16];
    int tid = threadIdx.x;
    int dir = blockIdx.z;
    int t0 = blockIdx.x * 16;
    if (tid < 16) {
        int tg = t0 + tid;
        rows[tid] = sent[dir ? (TT - 1 - tg) : tg];
    }
    __syncthreads();
    for (int i = 0; i < 16; i++) X[i][tid] = embed[(size_t)rows[i] * HD + tid];
    __syncthreads();
    int r = blockIdx.y * 256 + tid;
    const float* wrow = (dir ? wih_b : wih_f) + (size_t)r * HD;
    float acc[16];
#pragma unroll
    for (int i = 0; i < 16; i++) acc[i] = 0.0f;
    for (int kc = 0; kc < HD / 4; kc++) {
        float4 w4 = ((const float4*)wrow)[kc];
#pragma unroll
        for (int i = 0; i < 16; i++) {
            float4 x4 = *((const float4*)&X[i][kc * 4]);
            acc[i] += w4.x * x4.x + w4.y * x4.y + w4.z * x4.z + w4.w * x4.w;
        }
    }
    float bias = (dir ? b_b : b_f)[r];
    for (int i = 0; i < 16; i++)
        G[((size_t)dir * TT + t0 + i) * G4 + r] = acc[i] + bias;
}

// two-row int8 dot block: W0/W1 = 8 u32 (32 int8) of rows tid / tid+512;
// h2q u32 HB..HB+7, uniform-address broadcast reads shared by both chains.
#define DOTQ2(W0, W1, HB)                                                     \
    {                                                                         \
        uint4 pa = *((const uint4*)&h2q[(HB)]);                               \
        acc0 = sdot4e(W0[0], pa.x, acc0); acc1 = sdot4e(W1[0], pa.x, acc1);   \
        acc0 = sdot4e(W0[1], pa.y, acc0); acc1 = sdot4e(W1[1], pa.y, acc1);   \
        acc0 = sdot4e(W0[2], pa.z, acc0); acc1 = sdot4e(W1[2], pa.z, acc1);   \
        acc0 = sdot4e(W0[3], pa.w, acc0); acc1 = sdot4e(W1[3], pa.w, acc1);   \
        uint4 pb = *((const uint4*)&h2q[(HB) + 4]);                           \
        acc0 = sdot4e(W0[4], pb.x, acc0); acc1 = sdot4e(W1[4], pb.x, acc1);   \
        acc0 = sdot4e(W0[5], pb.y, acc0); acc1 = sdot4e(W1[5], pb.y, acc1);   \
        acc0 = sdot4e(W0[6], pb.z, acc0); acc1 = sdot4e(W1[6], pb.z, acc1);   \
        acc0 = sdot4e(W0[7], pb.w, acc0); acc1 = sdot4e(W1[7], pb.w, acc1);   \
    }

// K2: persistent per-direction LSTM recurrence, int8 (v_dot4), 512 threads,
// 2 gate rows each (tid, tid+512): thread j<256 owns (i_j,g_j), j+256 owns
// (f_j,o_j). ALL 128 weight u32 in SIXTEEN NAMED u32x8 SSA values: demand
// ~155 -> ~128 VGPR + ~27 AGPR (cheap v_accvgpr spills; R8 measured this mode
// as scratch-free). Zero per-step LDS weight traffic (R8's 64KB/step gone);
// only uniform h-broadcast DS reads remain, overlapped with the dot stream.
__global__ __launch_bounds__(512, 1)
void lstm_rec(const u32* wreg8, const float* rowscale,
              const float* G, const float* h0, const float* c0, float* H) {
    __shared__ float fo[2][256];           // sig(f), sig(o)
    __shared__ __align__(16) u32 h2q[64];  // 256 int8 of h (byte j = h[j])
    int tid = threadIdx.x;
    int dir = blockIdx.x;
    const u32x8* p0 = (const u32x8*)(wreg8 + ((size_t)dir * 1024 + tid) * 64);
    const u32x8* p1 = (const u32x8*)(wreg8 + ((size_t)dir * 1024 + tid + 512) * 64);
    u32x8 wq00 = p0[0], wq01 = p0[1], wq02 = p0[2], wq03 = p0[3],
          wq04 = p0[4], wq05 = p0[5], wq06 = p0[6], wq07 = p0[7];
    u32x8 wq10 = p1[0], wq11 = p1[1], wq12 = p1[2], wq13 = p1[3],
          wq14 = p1[4], wq15 = p1[5], wq16 = p1[6], wq17 = p1[7];
    float cr0 = rowscale[dir * 1024 + tid];
    float cr1 = rowscale[dir * 1024 + tid + 512];
    float cst = 0.0f;
    if (tid < 256) {
        cst = c0[dir * HD + tid];
        float hv = h0[dir * HD + tid];
        hv = fminf(fmaxf(hv, -1.984375f), 1.984375f);
        ((signed char*)h2q)[tid] = (signed char)(int)rintf(hv * 64.f);
    }
    __syncthreads();
    const float* Gd = G + (size_t)dir * TT * G4;
    float* Hd = H + (size_t)dir * TT * HD;
    for (int t = 0; t < TT; t++) {
        float g0 = Gd[(size_t)t * G4 + tid];          // issued early
        float g1 = Gd[(size_t)t * G4 + tid + 512];
        int acc0 = 0, acc1 = 0;
        DOTQ2(wq00, wq10, 0)  DOTQ2(wq01, wq11, 8)
        DOTQ2(wq02, wq12, 16) DOTQ2(wq03, wq13, 24)
        DOTQ2(wq04, wq14, 32) DOTQ2(wq05, wq15, 40)
        DOTQ2(wq06, wq16, 48) DOTQ2(wq07, wq17, 56)
        float e0 = (float)acc0 * cr0 + g0;
        float e1 = (float)acc1 * cr1 + g1;
        float x0, x1;
        if (tid >= 256) {                    // e0 = f_j, e1 = o_j  (j = tid-256)
            fo[0][tid - 256] = sigmf_(e0);
            fo[1][tid - 256] = sigmf_(e1);
        } else {                             // e0 = i_j, e1 = g_j: own transcendentals
            x0 = sigmf_(e0);                 // sig(i)
            x1 = tanhf_(e1);                 // tanh(g)
        }
        __syncthreads();
        if (tid < 256) {
            float sf = fo[0][tid], so = fo[1][tid];
            cst = sf * cst + x0 * x1;
            float h = so * tanhf_(cst);
            Hd[(size_t)t * HD + tid] = h;
            ((signed char*)h2q)[tid] = (signed char)(int)rintf(h * 64.f);  // |h|<1
        }
        __syncthreads();
    }
}

// K3: feats[t][n] = hf[t]·w_out[n][0:256] + hb_scan[T-1-t]·w_out[n][256:512] + b_out[n]
__global__ __launch_bounds__(256) void feats_kernel(const float* H, const float* w_out,
                                                    const float* b_out, float* feats) {
    int idx = blockIdx.x * blockDim.x + threadIdx.x;
    int t = idx >> 4, n = idx & 15;
    const float* hf = H + (size_t)t * HD;
    const float* hb = H + ((size_t)TT + (TT - 1 - t)) * HD;
    const float* w = w_out + (size_t)n * (2 * HD);
    float a = b_out[n];
    for (int k = 0; k < HD; k += 4) {
        float4 h4 = *((const float4*)&hf[k]);
        float4 w4 = *((const float4*)&w[k]);
        a += h4.x * w4.x + h4.y * w4.y + h4.z * w4.z + h4.w * w4.w;
    }
    for (int k = 0; k < HD; k += 4) {
        float4 h4 = *((const float4*)&hb[k]);
        float4 w4 = *((const float4*)&w[HD + k]);
        a += h4.x * w4.x + h4.y * w4.y + h4.z * w4.z + h4.w * w4.w;
    }
    feats[(size_t)t * NT + n] = a;
}

// K4: Viterbi + backtrack, single wave. Group result vft resident in all 4
// lanes of group n; one 4-gather shfl level + DPP butterfly per step.
__global__ __launch_bounds__(64) void viterbi_kernel(const float* feats, const float* trans,
                                                     float* out) {
    __shared__ float fl[4096];              // 16KB: 256 steps x 16 tags
    __shared__ float fvs[NT];
    __shared__ unsigned char bps[TT][NT];   // 32KB
    int lane = threadIdx.x;
    int n = lane >> 2, pg = lane & 3;
    float4 tr4 = *((const float4*)&trans[n * NT + pg * 4]);
    float vft = (n == START_TAG) ? 0.0f : NEGV;   // tag n's fv, replicated in group n
    for (int c = 0; c < TT / 256; c++) {
        float4 st[16];
        const float4* src = (const float4*)(feats + c * 4096);
#pragma unroll
        for (int i = 0; i < 16; i++) st[i] = src[i * 64 + lane];
#pragma unroll
        for (int i = 0; i < 16; i++) *((float4*)&fl[(i * 64 + lane) * 4]) = st[i];
        __syncthreads();
        for (int tt = 0; tt < 256; tt++) {
            int t = c * 256 + tt;
            float f0 = __shfl(vft, ((pg << 2) + 0) << 2, 64);
            float f1 = __shfl(vft, ((pg << 2) + 1) << 2, 64);
            float f2 = __shfl(vft, ((pg << 2) + 2) << 2, 64);
            float f3 = __shfl(vft, ((pg << 2) + 3) << 2, 64);
            float ft = fl[tt * 16 + n];
            float v = f0 + tr4.x; int bi = pg * 4 + 0;
            float v1 = f1 + tr4.y; if (v1 > v) { v = v1; bi = pg * 4 + 1; }
            float v2 = f2 + tr4.z; if (v2 > v) { v = v2; bi = pg * 4 + 2; }
            float v3 = f3 + tr4.w; if (v3 > v) { v = v3; bi = pg * 4 + 3; }
#pragma unroll
            for (int m = 1; m <= 2; m <<= 1) {   // DPP-speed; first-index tie-break
                float ov = __shfl_xor(v, m, 64);
                int ob = __shfl_xor(bi, m, 64);
                if (ov > v || (ov == v && ob < bi)) { v = ov; bi = ob; }
            }
            if (pg == 0) bps[t][n] = (unsigned char)bi;
            vft = v + ft;
        }
        __syncthreads();
    }
    if ((lane & 3) == 0) fvs[n] = vft;
    __syncthreads();
    if (lane == 0) {
        float best = -3.0e38f; int bt = 0;
        for (int p = 0; p < NT; p++) {
            float tv = fvs[p] + trans[STOP_TAG * NT + p];
            if (tv > best) { best = tv; bt = p; }
        }
        out[0] = best;
        int tag = bt;
        out[TT] = (float)tag;                  // path[T-1]
        for (int t = TT - 2; t >= 0; t--) {
            tag = bps[t + 1][tag];
            out[1 + t] = (float)tag;
        }
    }
}

extern "C" void kernel_launch(void* const* d_in, const int* in_sizes, int n_in,
                              void* d_out, int out_size, void* d_ws, size_t ws_size,
                              hipStream_t stream) {
    const int* sent = (const int*)d_in[0];
    const float* embed = (const float*)d_in[1];
    const float* wih_f = (const float*)d_in[2];
    const float* whh_f = (const float*)d_in[3];
    const float* b_f = (const float*)d_in[4];
    const float* wih_b = (const float*)d_in[5];
    const float* whh_b = (const float*)d_in[6];
    const float* b_b = (const float*)d_in[7];
    const float* w_out = (const float*)d_in[8];
    const float* b_out = (const float*)d_in[9];
    const float* trans = (const float*)d_in[10];
    const float* h0 = (const float*)d_in[11];
    const float* c0 = (const float*)d_in[12];
    float* out = (float*)d_out;
    char* ws = (char*)d_ws;

    float* G = (float*)(ws);                                    // 16MB
    float* H = (float*)(ws + (size_t)16 * 1024 * 1024);         // 4MB
    float* feats = (float*)(ws + (size_t)20 * 1024 * 1024);     // 128KB
    u32* wreg8 = (u32*)(ws + (size_t)21 * 1024 * 1024);         // 512KB
    float* rowscale = (float*)(ws + (size_t)22 * 1024 * 1024);  // 8KB

    pack_q8<<<dim3(512), 256, 0, stream>>>(whh_f, whh_b, wreg8, rowscale);
    input_gemm<<<dim3(TT / 16, G4 / 256, 2), 256, 0, stream>>>(sent, embed, wih_f, b_f,
                                                               wih_b, b_b, G);
    lstm_rec<<<dim3(2), 512, 0, stream>>>(wreg8, rowscale, G, h0, c0, H);
    feats_kernel<<<dim3(TT * NT / 256), 256, 0, stream>>>(H, w_out, b_out, feats);
    viterbi_kernel<<<dim3(1), 64, 0, stream>>>(feats, trans, out);
}